// Round 6
// baseline (283.421 us; speedup 1.0000x reference)
//
#include <hip/hip_runtime.h>
#include <hip/hip_bf16.h>

typedef __bf16 bf16;
typedef __attribute__((ext_vector_type(8))) __bf16 bf16x8;
typedef __attribute__((ext_vector_type(4))) __bf16 bf16x4v;
typedef __attribute__((ext_vector_type(4))) float f32x4;

#define B_  16
#define C_  256
#define HW_ 1024
#define PADR 1156              // 34*34 padded rows per z
#define ZSTR 295936            // 1156*256 elements per z in fTpad
#define TP  133                // transpose-tile LDS pad (8-distinct-bank stride)

__device__ __forceinline__ void gll16(const bf16* g, bf16* l) {
  __builtin_amdgcn_global_load_lds((const __attribute__((address_space(1))) void*)g,
                                   (__attribute__((address_space(3))) void*)l, 16, 0, 0);
}

// ---- fused rnorm + transpose into padded layout (borders zeroed here) + weight reorder.
// blocks [0,1024): rn[z][k] = 1/||f[z][:,k]||; fTpad[z][(h+1)*34+(w+1)][c] = bf16(f[z][c][h*32+w])
// blocks [1024,5632): Wr[t][c][d*256+cin] = w_t[c][cin][kh][kw]
__global__ void prep_fat(const float* __restrict__ f0, const float* __restrict__ f1,
                         const float* __restrict__ w0, const float* __restrict__ w1,
                         bf16* __restrict__ fTpad, float* __restrict__ rn,
                         bf16* __restrict__ Wr) {
  int tid = threadIdx.x;
  if (blockIdx.x >= 1024) {
    int i = (blockIdx.x - 1024) * 256 + tid;   // [0, 2*589824)
    int t = i / 589824, r2 = i % 589824;
    int c = r2 / 2304, r = r2 % 2304;
    int cin = r / 9, d = r % 9;
    Wr[(size_t)t * 589824 + c * 2304 + d * 256 + cin] = (bf16)(t ? w1 : w0)[r2];
    return;
  }
  __shared__ float sm[256][33];
  __shared__ float ps[8][32];
  int bx = blockIdx.x & 31, z = blockIdx.x >> 5;
  int t = z >> 4, b = z & 15;
  int k0 = bx * 32;                      // h = bx, k = k0 + w
  const float* fb = (t ? f1 : f0) + (size_t)b * C_ * HW_ + k0;
  int kk = tid & 31, cg = tid >> 5;
  float ssq = 0.f;
  #pragma unroll
  for (int i = 0; i < 32; ++i) {
    int c = cg + i * 8;
    float v = fb[(size_t)c * HW_ + kk];
    sm[c][kk] = v;
    ssq += v * v;
  }
  ps[cg][kk] = ssq;

  bf16x8 zv;
  #pragma unroll
  for (int e = 0; e < 8; ++e) zv[e] = (bf16)0.f;
  if (tid < 64) {
    int c = (tid & 31) * 8, side = tid >> 5;
    *(bf16x8*)(fTpad + ((size_t)z * PADR + (bx + 1) * 34 + side * 33) * C_ + c) = zv;
  }
  if (bx == 0 || bx == 31) {
    int prow = (bx == 0) ? 0 : 33;
    for (int q = tid; q < 34 * 32; q += 256) {
      int wcol = q >> 5, c = (q & 31) * 8;
      *(bf16x8*)(fTpad + ((size_t)z * PADR + prow * 34 + wcol) * C_ + c) = zv;
    }
  }

  __syncthreads();
  if (tid < 32) {
    float s = 0.f;
    #pragma unroll
    for (int r = 0; r < 8; ++r) s += ps[r][tid];
    rn[z * 1024 + k0 + tid] = 1.f / fmaxf(sqrtf(s), 1e-12f);
  }
  int wl = tid >> 3, c0 = (tid & 7) * 32;
  bf16* dst = fTpad + ((size_t)z * PADR + (bx + 1) * 34 + wl + 1) * C_ + c0;
  #pragma unroll
  for (int u = 0; u < 4; ++u) {
    bf16x8 vv;
    #pragma unroll
    for (int e = 0; e < 8; ++e) vv[e] = (bf16)sm[c0 + u * 8 + e][wl];
    *(bf16x8*)(dst + u * 8) = vv;
  }
}

// ---- grouped 3x3 fusion conv over BOTH tasks; writes M row (b,i) IN PLACE over aff0 row (b,i)
__global__ void fusion_conv2(const bf16* __restrict__ aff, const float* __restrict__ fw,
                             const float* __restrict__ fb, bf16* __restrict__ M) {
  __shared__ float sa[2][1024];
  int bi = blockIdx.x;           // b*1024 + i
  int i = bi & 1023, b = bi >> 10;
  int tid = threadIdx.x;
  #pragma unroll
  for (int t = 0; t < 2; ++t) {
    const bf16* arow = aff + (((size_t)t * 16 + b) * 1024 + i) * 1024;
    bf16x4v ch = ((const bf16x4v*)arow)[tid];
    sa[t][tid * 4 + 0] = (float)ch[0];
    sa[t][tid * 4 + 1] = (float)ch[1];
    sa[t][tid * 4 + 2] = (float)ch[2];
    sa[t][tid * 4 + 3] = (float)ch[3];
  }
  float wgt[2][9];
  #pragma unroll
  for (int t = 0; t < 2; ++t)
    #pragma unroll
    for (int q = 0; q < 9; ++q) wgt[t][q] = fw[i * 18 + t * 9 + q];
  float bias = fb[i];
  __syncthreads();
  #pragma unroll
  for (int s0 = 0; s0 < 4; ++s0) {
    int s = tid + s0 * 256;
    int h = s >> 5, w = s & 31;
    float acc = bias;
    #pragma unroll
    for (int kh = 0; kh < 3; ++kh) {
      int hh = h + kh - 1;
      if ((unsigned)hh < 32u) {
        #pragma unroll
        for (int kw = 0; kw < 3; ++kw) {
          int ww = w + kw - 1;
          if ((unsigned)ww < 32u) {
            acc += wgt[0][kh * 3 + kw] * sa[0][hh * 32 + ww];
            acc += wgt[1][kh * 3 + kw] * sa[1][hh * 32 + ww];
          }
        }
      }
    }
    M[((size_t)bi << 10) + s] = (bf16)acc;
  }
}

// ---------------- NT GEMM core (m97 structure): C[m,n] = sum_k A[m,k]*B[n,k], 128x128 tile ----
// MODE 1: aff SYRK, upper-triangle tiles only (by<=bx); mirror via LDS transpose.
// MODE 2: attend; z pair-major: A=value[z], B=Mbuf[b]; fp32 0.5*C + 0.5*feat epilogue.
template<int MODE, int BM>
__device__ __forceinline__
void gemm_core(int bx, int by, int z, bf16* As, bf16* Bs, bf16* T,
               const bf16* __restrict__ A, long long sA,
               const bf16* __restrict__ Bm, long long sB, int K,
               bf16* __restrict__ Cb, long long sC,
               const float* __restrict__ x0, const float* __restrict__ x1,
               float* __restrict__ Co) {
  const int tt = (MODE == 1) ? (z >> 4) : (z & 1);
  const int bb = (MODE == 1) ? (z & 15) : (z >> 1);
  const int zold = tt * 16 + bb;
  const bf16* Ab = A + (size_t)z * sA;
  const bf16* Bb = Bm + (size_t)(MODE == 1 ? z : bb) * sB;
  const int m0 = by * BM, n0 = bx * 128;
  const int tid = threadIdx.x;
  const int lane = tid & 63, wave = tid >> 6;
  const int wm = (wave >> 1) * (BM / 2), wn = (wave & 1) * 64;
  const int fr = lane & 15, fq = lane >> 4;
  constexpr int MI = BM / 32;
  constexpr int SA = BM / 32;

  const bf16* srcA[SA];
  const bf16* srcB[4];
  int ldsA[SA], ldsB[4];
  #pragma unroll
  for (int s = 0; s < SA; ++s) {
    int q = (wave * SA + s) * 64 + lane;
    int row = q >> 3, c = (q & 7) ^ (row & 7);
    ldsA[s] = __builtin_amdgcn_readfirstlane((wave * SA + s) * 512);
    if (MODE == 1) {
      int j = m0 + row;
      srcA[s] = Ab + (size_t)(((j >> 5) + 1) * 34 + (j & 31) + 1) * C_ + c * 8;
    } else {
      srcA[s] = Ab + (size_t)(m0 + row) * K + c * 8;
    }
  }
  #pragma unroll
  for (int s = 0; s < 4; ++s) {
    int q = (wave * 4 + s) * 64 + lane;
    int row = q >> 3, c = (q & 7) ^ (row & 7);
    ldsB[s] = __builtin_amdgcn_readfirstlane((wave * 4 + s) * 512);
    int jb = n0 + row;
    if (MODE == 1) {
      srcB[s] = Bb + (size_t)(((jb >> 5) + 1) * 34 + (jb & 31) + 1) * C_ + c * 8;
    } else {
      srcB[s] = Bb + (size_t)jb * K + c * 8;
    }
  }
  int lA[2][MI], lB[2][4];
  #pragma unroll
  for (int h = 0; h < 2; ++h) {
    #pragma unroll
    for (int i = 0; i < MI; ++i) {
      int rr = wm + i * 16 + fr;
      lA[h][i] = rr * 64 + (((h * 4) + fq) ^ (rr & 7)) * 8;
    }
    #pragma unroll
    for (int j = 0; j < 4; ++j) {
      int rc = wn + j * 16 + fr;
      lB[h][j] = rc * 64 + (((h * 4) + fq) ^ (rc & 7)) * 8;
    }
  }

  f32x4 acc[MI][4];
  #pragma unroll
  for (int i = 0; i < MI; ++i)
    #pragma unroll
    for (int j = 0; j < 4; ++j) acc[i][j] = 0.f;

  for (int k0 = 0; k0 < K; k0 += 64) {
    #pragma unroll
    for (int s = 0; s < SA; ++s) gll16(srcA[s] + k0, As + ldsA[s]);
    #pragma unroll
    for (int s = 0; s < 4; ++s) gll16(srcB[s] + k0, Bs + ldsB[s]);
    __syncthreads();
    #pragma unroll
    for (int h = 0; h < 2; ++h) {
      bf16x8 af[MI], bfr[4];
      #pragma unroll
      for (int i = 0; i < MI; ++i) af[i] = *(const bf16x8*)(&As[lA[h][i]]);
      #pragma unroll
      for (int j = 0; j < 4; ++j) bfr[j] = *(const bf16x8*)(&Bs[lB[h][j]]);
      #pragma unroll
      for (int i = 0; i < MI; ++i)
        #pragma unroll
        for (int j = 0; j < 4; ++j)
          acc[i][j] = __builtin_amdgcn_mfma_f32_16x16x32_bf16(af[i], bfr[j], acc[i][j], 0, 0, 0);
    }
    __syncthreads();
  }

  // epilogue: D element (reg r, lane) -> row = quad*4 + r, col = lane&15  [m89/m91]
  const bool mirror = (MODE == 1) && (bx != by);
  #pragma unroll
  for (int i = 0; i < MI; ++i) {
    int rbase = m0 + wm + i * 16 + fq * 4;
    #pragma unroll
    for (int j = 0; j < 4; ++j) {
      int col = n0 + wn + j * 16 + fr;
      float cj = (MODE == 1) ? x0[(size_t)z * 1024 + col] : 0.f;
      #pragma unroll
      for (int r = 0; r < 4; ++r) {
        int row = rbase + r;
        float v = acc[i][j][r];
        if (MODE == 1) {
          bf16 sv = (bf16)(v * x0[(size_t)z * 1024 + row] * cj);
          Cb[(size_t)z * sC + (size_t)row * 1024 + col] = sv;
          if (mirror) T[(row - m0) * TP + (col - n0)] = sv;
        } else {
          const float* fp = tt ? x1 : x0;
          Co[(size_t)zold * sC + (size_t)row * 1024 + col] =
              0.5f * v + 0.5f * fp[(size_t)bb * sC + (size_t)row * 1024 + col];
        }
      }
    }
  }
  if (mirror) {
    __syncthreads();
    // write transposed tile at (bx,by): out row = n0-local g, out col = m0-local c
    #pragma unroll
    for (int s = 0; s < 8; ++s) {
      int q2 = s * 256 + tid;            // 2048 16B chunks
      int g = q2 >> 4, c0 = (q2 & 15) << 3;
      bf16x8 vv;
      #pragma unroll
      for (int e = 0; e < 8; ++e) vv[e] = T[(c0 + e) * TP + g];
      *(bf16x8*)(Cb + (size_t)z * sC + (size_t)(n0 + g) * 1024 + m0 + c0) = vv;
    }
  }
}

__global__ __launch_bounds__(256, 4)
void gemm_aff(const bf16* __restrict__ fTpad, const float* __restrict__ rn,
              bf16* __restrict__ aff) {
  __shared__ bf16 smem[128 * TP];        // 17024 elems >= 2*8192 (As+Bs) ; T aliases base
  int q = blockIdx.x, by = 0, cnt = 8;
  while (q >= cnt) { q -= cnt; ++by; --cnt; }
  int bx = by + q;
  gemm_core<1, 128>(bx, by, blockIdx.z, smem, smem + 8192, smem,
                    fTpad, ZSTR, fTpad, ZSTR, C_,
                    aff, (long long)HW_ * HW_, rn, rn, nullptr);
}

__global__ __launch_bounds__(256, 4)
void gemm_attend(const bf16* __restrict__ value, const bf16* __restrict__ Mbuf,
                 const float* __restrict__ f0, const float* __restrict__ f1,
                 float* __restrict__ out) {
  __shared__ bf16 smem[128 * 128];
  gemm_core<2, 128>(blockIdx.x, blockIdx.y, blockIdx.z, smem, smem + 8192, smem,
                    value, (long long)C_ * HW_, Mbuf, (long long)HW_ * HW_, 1024,
                    nullptr, (long long)C_ * HW_, f0, f1, out);
}

// ---------------- pipelined value-conv GEMM: 256M x 128N x BK64, 8 waves, 512 thr ----
// value[zp][c][j] = sum_{d,cin} Wr[t][c][d*256+cin] * fTpad[zold][pad(j)+shift(d)][cin] + bias
// grid (8 N-tiles, 32 z) = 256 blocks = 1/CU.
// Round-6: A-operand (Wr, 1.2 MB/task, L2-resident) bypasses LDS entirely -- loaded
// global->VGPR per K-step, double-buffered by loop-parity (static indexing, rule #20).
// Rationale: the 256x128/8-wave tile's LDS traffic (128 KB reads + 49 KB writes per
// K-step ~ 1400-1700 cyc) EXCEEDED the MFMA pipe time (1242 cyc) -- LDS BW was the
// ceiling rounds 3-5 kept hitting. B-only LDS: 64 KB read + 16 KB write ~ 700 cyc.
// B stays triple-buffered via gll16 with counted vmcnt(2) (T4): issue order per step
// is [8 A-loads (phase A) ... 2 B-gll16 (phase B, LAST)], so vmcnt(2) at step end
// leaves exactly the newest B-pair in flight and proves B(t+1) (issued step t-1)
// landed. A-load waits are compiler-tracked (VGPR dest). Buffer hazard proof as
// rounds 3-5: the barrier ending step t-1 separates all readers of buf[(t+2)%3]
// from its overwrite in step t.
#define VP_KSTEP(T_, ACUR, ANXT)                                               \
  {                                                                            \
    const int t_ = (T_);                                                       \
    bf16* Bs_ = smem3 + (t_ % 3) * 8192;                                       \
    /* ---- phase A (h=0): B ds_reads + A(t+1) global prefetch + MFMA ---- */  \
    {                                                                          \
      bf16x8 bv[4];                                                            \
      _Pragma("unroll")                                                        \
      for (int j = 0; j < 4; ++j) bv[j] = *(const bf16x8*)(Bs_ + lB[0][j]);    \
      if (t_ + 1 < 36) {                                                       \
        _Pragma("unroll")                                                      \
        for (int h = 0; h < 2; ++h)                                            \
          _Pragma("unroll")                                                    \
          for (int i = 0; i < 4; ++i)                                          \
            ANXT[h][i] = *(const bf16x8*)(srcAr[i] + (t_ + 1) * 64 + h * 32);  \
      }                                                                        \
      asm volatile("s_waitcnt lgkmcnt(0)" ::: "memory");                       \
      __builtin_amdgcn_sched_barrier(0);                                       \
      __builtin_amdgcn_s_setprio(1);                                           \
      _Pragma("unroll")                                                        \
      for (int i = 0; i < 4; ++i)                                              \
        _Pragma("unroll")                                                      \
        for (int j = 0; j < 4; ++j)                                            \
          acc[i][j] = __builtin_amdgcn_mfma_f32_16x16x32_bf16(                 \
              ACUR[0][i], bv[j], acc[i][j], 0, 0, 0);                          \
      __builtin_amdgcn_s_setprio(0);                                           \
    }                                                                          \
    __builtin_amdgcn_s_barrier();                                              \
    /* ---- phase B (h=1): B ds_reads + B(t+2) stage + MFMA + counted wait */  \
    {                                                                          \
      bf16x8 bv[4];                                                            \
      _Pragma("unroll")                                                        \
      for (int j = 0; j < 4; ++j) bv[j] = *(const bf16x8*)(Bs_ + lB[1][j]);    \
      if (t_ + 2 < 36) STAGE_B(t_ + 2, (t_ + 2) % 3);                          \
      asm volatile("s_waitcnt lgkmcnt(0)" ::: "memory");                       \
      __builtin_amdgcn_sched_barrier(0);                                       \
      __builtin_amdgcn_s_setprio(1);                                           \
      _Pragma("unroll")                                                        \
      for (int i = 0; i < 4; ++i)                                              \
        _Pragma("unroll")                                                      \
        for (int j = 0; j < 4; ++j)                                            \
          acc[i][j] = __builtin_amdgcn_mfma_f32_16x16x32_bf16(                 \
              ACUR[1][i], bv[j], acc[i][j], 0, 0, 0);                          \
      __builtin_amdgcn_s_setprio(0);                                           \
      if (t_ < 34) asm volatile("s_waitcnt vmcnt(2)" ::: "memory");            \
      else         asm volatile("s_waitcnt vmcnt(0)" ::: "memory");            \
    }                                                                          \
    __builtin_amdgcn_s_barrier();                                              \
  }

__global__ __launch_bounds__(512, 2)
void gemm_value_p(const bf16* __restrict__ Wr, const bf16* __restrict__ fTpad,
                  bf16* __restrict__ value, const float* __restrict__ b0,
                  const float* __restrict__ b1) {
  __shared__ bf16 smem3[3 * 8192];       // B triple buffer, 48 KB
  const int z = blockIdx.y;              // pair-major: t = z&1, b = z>>1
  const int tt = z & 1, bb = z >> 1, zold = tt * 16 + bb;
  const bf16* Ab = Wr + (size_t)tt * 589824;
  const bf16* Bb = fTpad + (size_t)zold * ZSTR;
  const int n0 = blockIdx.x * 128;
  const int tid = threadIdx.x;
  const int lane = tid & 63, wave = tid >> 6;
  const int wm = (wave >> 1) * 64, wn = (wave & 1) * 64;   // 4M x 2N wave grid, 64x64/wave
  const int fr = lane & 15, fq = lane >> 4;

  // A-fragment source pointers: row = wm + i*16 + fr, k-base = fq*8 (16B contiguous)
  const bf16* srcAr[4];
  #pragma unroll
  for (int i = 0; i < 4; ++i)
    srcAr[i] = Ab + (size_t)(wm + i * 16 + fr) * 2304 + fq * 8;

  // B staging: XOR chunk swizzle p = c ^ (row & 7), linear LDS dest (m173)
  const bf16* srcB[2]; int ldsB[2];
  #pragma unroll
  for (int s = 0; s < 2; ++s) {
    int q = s * 512 + tid;               // 1024 chunks cover B 128x64
    int row = q >> 3, c = (q & 7) ^ (row & 7);
    ldsB[s] = __builtin_amdgcn_readfirstlane(s * 4096 + wave * 512);
    int jb = n0 + row;
    srcB[s] = Bb + (size_t)(((jb >> 5) + 1) * 34 + (jb & 31) + 1) * C_ + c * 8;
  }

  int lB[2][4];
  #pragma unroll
  for (int h = 0; h < 2; ++h)
    #pragma unroll
    for (int j = 0; j < 4; ++j) {
      int rc = wn + j * 16 + fr;
      lB[h][j] = rc * 64 + (((h * 4) + fq) ^ (rc & 7)) * 8;
    }

  auto STAGE_B = [&](int t, int bufi) {
    int k0 = t * 64;
    int d = k0 >> 8;                     // 3x3 tap index, 4 K-steps per tap
    int kh = d / 3, kw = d - kh * 3;
    int boff = ((kh - 1) * 34 + (kw - 1)) * C_ + (k0 & 255);
    bf16* Bs = smem3 + bufi * 8192;
    gll16(srcB[0] + boff, Bs + ldsB[0]);
    gll16(srcB[1] + boff, Bs + ldsB[1]);
  };

  f32x4 acc[4][4];
  #pragma unroll
  for (int i = 0; i < 4; ++i)
    #pragma unroll
    for (int j = 0; j < 4; ++j) acc[i][j] = 0.f;

  bf16x8 a0[2][4], a1[2][4];             // parity double-buffer for A fragments
  #pragma unroll
  for (int h = 0; h < 2; ++h)
    #pragma unroll
    for (int i = 0; i < 4; ++i)
      a0[h][i] = *(const bf16x8*)(srcAr[i] + h * 32);    // k0 = 0
  __builtin_amdgcn_sched_barrier(0);
  STAGE_B(0, 0);
  STAGE_B(1, 1);
  __builtin_amdgcn_sched_barrier(0);
  // FIFO [8x A(0), 2x B(0), 2x B(1)]: vmcnt(2) drains A(0)+B(0), leaves B(1) flying
  asm volatile("s_waitcnt vmcnt(2)" ::: "memory");
  __builtin_amdgcn_s_barrier();

  #pragma unroll 1
  for (int tp = 0; tp < 18; ++tp) {
    VP_KSTEP(2 * tp,     a0, a1);
    VP_KSTEP(2 * tp + 1, a1, a0);
  }

  // epilogue: row = wm + i*16 + fq*4 + r (= out channel c), col = n0 + wn + j*16 + fr
  const float* bias = tt ? b1 : b0;
  #pragma unroll
  for (int i = 0; i < 4; ++i) {
    #pragma unroll
    for (int j = 0; j < 4; ++j) {
      int col = n0 + wn + j * 16 + fr;
      #pragma unroll
      for (int r = 0; r < 4; ++r) {
        int row = wm + i * 16 + fq * 4 + r;
        value[(size_t)z * ((size_t)C_ * HW_) + (size_t)row * 1024 + col] =
            (bf16)(acc[i][j][r] + bias[row]);
      }
    }
  }
}

extern "C" void kernel_launch(void* const* d_in, const int* in_sizes, int n_in,
                              void* d_out, int out_size, void* d_ws, size_t ws_size,
                              hipStream_t stream) {
  const float* f0 = (const float*)d_in[0];
  const float* f1 = (const float*)d_in[1];
  const float* w0 = (const float*)d_in[2];
  const float* b0 = (const float*)d_in[3];
  const float* w1 = (const float*)d_in[4];
  const float* b1 = (const float*)d_in[5];
  const float* fusion_w = (const float*)d_in[6];
  const float* fusion_b = (const float*)d_in[7];
  float* out = (float*)d_out;

  // workspace (~105 MB peak):
  //   aff [2 tasks] at 0..67.1M; Mbuf written IN PLACE over aff0 by fusion_conv2;
  //   fTpad / Wr / value / rn above (value kept separate from aff).
  char* ws = (char*)d_ws;
  bf16* aff   = (bf16*)ws;                       // 67,108,864  [2 tasks]
  bf16* Mbuf  = (bf16*)ws;                       // in-place over aff0
  bf16* fTpad = (bf16*)(ws + 67108864ull);       // 18,939,904
  bf16* Wr    = (bf16*)(ws + 86048768ull);       //  2,359,296
  bf16* value = (bf16*)(ws + 88408064ull);       // 16,777,216
  float* rn   = (float*)(ws + 105185280ull);     //    131,072

  prep_fat<<<5632, 256, 0, stream>>>(f0, f1, w0, w1, fTpad, rn, Wr);
  // aff[z][i][j] = (sum_c fT[z][i][c] * fT[z][j][c]) * rn[z][i] * rn[z][j]  (SYRK, 36 tiles/z)
  gemm_aff<<<dim3(36, 1, 32), 256, 0, stream>>>(fTpad, rn, aff);
  // value[zp][c][j] = conv(f_t, w_t)[b][c][j] + bias_t[c]   (pipelined 8-wave, A-in-regs)
  gemm_value_p<<<dim3(8, 32), 512, 0, stream>>>(Wr, fTpad, value, b0, b1);
  fusion_conv2<<<16384, 256, 0, stream>>>(aff, fusion_w, fusion_b, Mbuf);
  // out[t][b][c][j] = 0.5 * sum_k value[zp][c][k] * Mbuf[b][j][k] + 0.5 * f_t[b][c][j]
  gemm_attend<<<dim3(8, 2, 32), 256, 0, stream>>>(value, Mbuf, f0, f1, out);
}

// Round 7
// 227.302 us; speedup vs baseline: 1.2469x; 1.2469x over previous
//
#include <hip/hip_runtime.h>
#include <hip/hip_bf16.h>

typedef __bf16 bf16;
typedef __attribute__((ext_vector_type(8))) __bf16 bf16x8;
typedef __attribute__((ext_vector_type(4))) __bf16 bf16x4v;
typedef __attribute__((ext_vector_type(4))) float f32x4;

#define B_  16
#define C_  256
#define HW_ 1024
#define PADR 1156              // 34*34 padded rows per z
#define ZSTR 295936            // 1156*256 elements per z in fTpad
#define TP  133                // transpose-tile LDS pad (8-distinct-bank stride)

__device__ __forceinline__ void gll16(const bf16* g, bf16* l) {
  __builtin_amdgcn_global_load_lds((const __attribute__((address_space(1))) void*)g,
                                   (__attribute__((address_space(3))) void*)l, 16, 0, 0);
}

// ---- fused rnorm + transpose into padded layout (borders zeroed here) + weight reorder.
// blocks [0,1024): rn[z][k] = 1/||f[z][:,k]||; fTpad[z][(h+1)*34+(w+1)][c] = bf16(f[z][c][h*32+w])
// blocks [1024,5632): Wr[t][c][d*256+cin] = w_t[c][cin][kh][kw]
__global__ void prep_fat(const float* __restrict__ f0, const float* __restrict__ f1,
                         const float* __restrict__ w0, const float* __restrict__ w1,
                         bf16* __restrict__ fTpad, float* __restrict__ rn,
                         bf16* __restrict__ Wr) {
  int tid = threadIdx.x;
  if (blockIdx.x >= 1024) {
    int i = (blockIdx.x - 1024) * 256 + tid;   // [0, 2*589824)
    int t = i / 589824, r2 = i % 589824;
    int c = r2 / 2304, r = r2 % 2304;
    int cin = r / 9, d = r % 9;
    Wr[(size_t)t * 589824 + c * 2304 + d * 256 + cin] = (bf16)(t ? w1 : w0)[r2];
    return;
  }
  __shared__ float sm[256][33];
  __shared__ float ps[8][32];
  int bx = blockIdx.x & 31, z = blockIdx.x >> 5;
  int t = z >> 4, b = z & 15;
  int k0 = bx * 32;                      // h = bx, k = k0 + w
  const float* fb = (t ? f1 : f0) + (size_t)b * C_ * HW_ + k0;
  int kk = tid & 31, cg = tid >> 5;
  float ssq = 0.f;
  #pragma unroll
  for (int i = 0; i < 32; ++i) {
    int c = cg + i * 8;
    float v = fb[(size_t)c * HW_ + kk];
    sm[c][kk] = v;
    ssq += v * v;
  }
  ps[cg][kk] = ssq;

  bf16x8 zv;
  #pragma unroll
  for (int e = 0; e < 8; ++e) zv[e] = (bf16)0.f;
  if (tid < 64) {
    int c = (tid & 31) * 8, side = tid >> 5;
    *(bf16x8*)(fTpad + ((size_t)z * PADR + (bx + 1) * 34 + side * 33) * C_ + c) = zv;
  }
  if (bx == 0 || bx == 31) {
    int prow = (bx == 0) ? 0 : 33;
    for (int q = tid; q < 34 * 32; q += 256) {
      int wcol = q >> 5, c = (q & 31) * 8;
      *(bf16x8*)(fTpad + ((size_t)z * PADR + prow * 34 + wcol) * C_ + c) = zv;
    }
  }

  __syncthreads();
  if (tid < 32) {
    float s = 0.f;
    #pragma unroll
    for (int r = 0; r < 8; ++r) s += ps[r][tid];
    rn[z * 1024 + k0 + tid] = 1.f / fmaxf(sqrtf(s), 1e-12f);
  }
  int wl = tid >> 3, c0 = (tid & 7) * 32;
  bf16* dst = fTpad + ((size_t)z * PADR + (bx + 1) * 34 + wl + 1) * C_ + c0;
  #pragma unroll
  for (int u = 0; u < 4; ++u) {
    bf16x8 vv;
    #pragma unroll
    for (int e = 0; e < 8; ++e) vv[e] = (bf16)sm[c0 + u * 8 + e][wl];
    *(bf16x8*)(dst + u * 8) = vv;
  }
}

// ---- grouped 3x3 fusion conv over BOTH tasks; writes M row (b,i) IN PLACE over aff0 row (b,i)
__global__ void fusion_conv2(const bf16* __restrict__ aff, const float* __restrict__ fw,
                             const float* __restrict__ fb, bf16* __restrict__ M) {
  __shared__ float sa[2][1024];
  int bi = blockIdx.x;           // b*1024 + i
  int i = bi & 1023, b = bi >> 10;
  int tid = threadIdx.x;
  #pragma unroll
  for (int t = 0; t < 2; ++t) {
    const bf16* arow = aff + (((size_t)t * 16 + b) * 1024 + i) * 1024;
    bf16x4v ch = ((const bf16x4v*)arow)[tid];
    sa[t][tid * 4 + 0] = (float)ch[0];
    sa[t][tid * 4 + 1] = (float)ch[1];
    sa[t][tid * 4 + 2] = (float)ch[2];
    sa[t][tid * 4 + 3] = (float)ch[3];
  }
  float wgt[2][9];
  #pragma unroll
  for (int t = 0; t < 2; ++t)
    #pragma unroll
    for (int q = 0; q < 9; ++q) wgt[t][q] = fw[i * 18 + t * 9 + q];
  float bias = fb[i];
  __syncthreads();
  #pragma unroll
  for (int s0 = 0; s0 < 4; ++s0) {
    int s = tid + s0 * 256;
    int h = s >> 5, w = s & 31;
    float acc = bias;
    #pragma unroll
    for (int kh = 0; kh < 3; ++kh) {
      int hh = h + kh - 1;
      if ((unsigned)hh < 32u) {
        #pragma unroll
        for (int kw = 0; kw < 3; ++kw) {
          int ww = w + kw - 1;
          if ((unsigned)ww < 32u) {
            acc += wgt[0][kh * 3 + kw] * sa[0][hh * 32 + ww];
            acc += wgt[1][kh * 3 + kw] * sa[1][hh * 32 + ww];
          }
        }
      }
    }
    M[((size_t)bi << 10) + s] = (bf16)acc;
  }
}

// ---------------- NT GEMM core (m97 structure): C[m,n] = sum_k A[m,k]*B[n,k], 128x128 tile ----
// MODE 1: aff SYRK, upper-triangle tiles only (by<=bx); mirror via LDS transpose.
// MODE 2: attend; z pair-major: A=value[z], B=Mbuf[b]; fp32 0.5*C + 0.5*feat epilogue.
template<int MODE, int BM>
__device__ __forceinline__
void gemm_core(int bx, int by, int z, bf16* As, bf16* Bs, bf16* T,
               const bf16* __restrict__ A, long long sA,
               const bf16* __restrict__ Bm, long long sB, int K,
               bf16* __restrict__ Cb, long long sC,
               const float* __restrict__ x0, const float* __restrict__ x1,
               float* __restrict__ Co) {
  const int tt = (MODE == 1) ? (z >> 4) : (z & 1);
  const int bb = (MODE == 1) ? (z & 15) : (z >> 1);
  const int zold = tt * 16 + bb;
  const bf16* Ab = A + (size_t)z * sA;
  const bf16* Bb = Bm + (size_t)(MODE == 1 ? z : bb) * sB;
  const int m0 = by * BM, n0 = bx * 128;
  const int tid = threadIdx.x;
  const int lane = tid & 63, wave = tid >> 6;
  const int wm = (wave >> 1) * (BM / 2), wn = (wave & 1) * 64;
  const int fr = lane & 15, fq = lane >> 4;
  constexpr int MI = BM / 32;
  constexpr int SA = BM / 32;

  const bf16* srcA[SA];
  const bf16* srcB[4];
  int ldsA[SA], ldsB[4];
  #pragma unroll
  for (int s = 0; s < SA; ++s) {
    int q = (wave * SA + s) * 64 + lane;
    int row = q >> 3, c = (q & 7) ^ (row & 7);
    ldsA[s] = __builtin_amdgcn_readfirstlane((wave * SA + s) * 512);
    if (MODE == 1) {
      int j = m0 + row;
      srcA[s] = Ab + (size_t)(((j >> 5) + 1) * 34 + (j & 31) + 1) * C_ + c * 8;
    } else {
      srcA[s] = Ab + (size_t)(m0 + row) * K + c * 8;
    }
  }
  #pragma unroll
  for (int s = 0; s < 4; ++s) {
    int q = (wave * 4 + s) * 64 + lane;
    int row = q >> 3, c = (q & 7) ^ (row & 7);
    ldsB[s] = __builtin_amdgcn_readfirstlane((wave * 4 + s) * 512);
    int jb = n0 + row;
    if (MODE == 1) {
      srcB[s] = Bb + (size_t)(((jb >> 5) + 1) * 34 + (jb & 31) + 1) * C_ + c * 8;
    } else {
      srcB[s] = Bb + (size_t)jb * K + c * 8;
    }
  }
  int lA[2][MI], lB[2][4];
  #pragma unroll
  for (int h = 0; h < 2; ++h) {
    #pragma unroll
    for (int i = 0; i < MI; ++i) {
      int rr = wm + i * 16 + fr;
      lA[h][i] = rr * 64 + (((h * 4) + fq) ^ (rr & 7)) * 8;
    }
    #pragma unroll
    for (int j = 0; j < 4; ++j) {
      int rc = wn + j * 16 + fr;
      lB[h][j] = rc * 64 + (((h * 4) + fq) ^ (rc & 7)) * 8;
    }
  }

  f32x4 acc[MI][4];
  #pragma unroll
  for (int i = 0; i < MI; ++i)
    #pragma unroll
    for (int j = 0; j < 4; ++j) acc[i][j] = 0.f;

  for (int k0 = 0; k0 < K; k0 += 64) {
    #pragma unroll
    for (int s = 0; s < SA; ++s) gll16(srcA[s] + k0, As + ldsA[s]);
    #pragma unroll
    for (int s = 0; s < 4; ++s) gll16(srcB[s] + k0, Bs + ldsB[s]);
    __syncthreads();
    #pragma unroll
    for (int h = 0; h < 2; ++h) {
      bf16x8 af[MI], bfr[4];
      #pragma unroll
      for (int i = 0; i < MI; ++i) af[i] = *(const bf16x8*)(&As[lA[h][i]]);
      #pragma unroll
      for (int j = 0; j < 4; ++j) bfr[j] = *(const bf16x8*)(&Bs[lB[h][j]]);
      #pragma unroll
      for (int i = 0; i < MI; ++i)
        #pragma unroll
        for (int j = 0; j < 4; ++j)
          acc[i][j] = __builtin_amdgcn_mfma_f32_16x16x32_bf16(af[i], bfr[j], acc[i][j], 0, 0, 0);
    }
    __syncthreads();
  }

  // epilogue: D element (reg r, lane) -> row = quad*4 + r, col = lane&15  [m89/m91]
  const bool mirror = (MODE == 1) && (bx != by);
  #pragma unroll
  for (int i = 0; i < MI; ++i) {
    int rbase = m0 + wm + i * 16 + fq * 4;
    #pragma unroll
    for (int j = 0; j < 4; ++j) {
      int col = n0 + wn + j * 16 + fr;
      float cj = (MODE == 1) ? x0[(size_t)z * 1024 + col] : 0.f;
      #pragma unroll
      for (int r = 0; r < 4; ++r) {
        int row = rbase + r;
        float v = acc[i][j][r];
        if (MODE == 1) {
          bf16 sv = (bf16)(v * x0[(size_t)z * 1024 + row] * cj);
          Cb[(size_t)z * sC + (size_t)row * 1024 + col] = sv;
          if (mirror) T[(row - m0) * TP + (col - n0)] = sv;
        } else {
          const float* fp = tt ? x1 : x0;
          Co[(size_t)zold * sC + (size_t)row * 1024 + col] =
              0.5f * v + 0.5f * fp[(size_t)bb * sC + (size_t)row * 1024 + col];
        }
      }
    }
  }
  if (mirror) {
    __syncthreads();
    // write transposed tile at (bx,by): out row = n0-local g, out col = m0-local c
    #pragma unroll
    for (int s = 0; s < 8; ++s) {
      int q2 = s * 256 + tid;            // 2048 16B chunks
      int g = q2 >> 4, c0 = (q2 & 15) << 3;
      bf16x8 vv;
      #pragma unroll
      for (int e = 0; e < 8; ++e) vv[e] = T[(c0 + e) * TP + g];
      *(bf16x8*)(Cb + (size_t)z * sC + (size_t)(n0 + g) * 1024 + m0 + c0) = vv;
    }
  }
}

__global__ __launch_bounds__(256, 4)
void gemm_aff(const bf16* __restrict__ fTpad, const float* __restrict__ rn,
              bf16* __restrict__ aff) {
  __shared__ bf16 smem[128 * TP];        // 17024 elems >= 2*8192 (As+Bs) ; T aliases base
  int q = blockIdx.x, by = 0, cnt = 8;
  while (q >= cnt) { q -= cnt; ++by; --cnt; }
  int bx = by + q;
  gemm_core<1, 128>(bx, by, blockIdx.z, smem, smem + 8192, smem,
                    fTpad, ZSTR, fTpad, ZSTR, C_,
                    aff, (long long)HW_ * HW_, rn, rn, nullptr);
}

__global__ __launch_bounds__(256, 4)
void gemm_attend(const bf16* __restrict__ value, const bf16* __restrict__ Mbuf,
                 const float* __restrict__ f0, const float* __restrict__ f1,
                 float* __restrict__ out) {
  __shared__ bf16 smem[128 * 128];
  gemm_core<2, 128>(blockIdx.x, blockIdx.y, blockIdx.z, smem, smem + 8192, smem,
                    value, (long long)C_ * HW_, Mbuf, (long long)HW_ * HW_, 1024,
                    nullptr, (long long)C_ * HW_, f0, f1, out);
}

// ---------------- pipelined value-conv GEMM: 256M x 128N x BK64, 8 waves, 512 thr ----
// value[zp][c][j] = sum_{d,cin} Wr[t][c][d*256+cin] * fTpad[zold][pad(j)+shift(d)][cin] + bias
// grid (8 N-tiles, 32 z) = 256 blocks = 1/CU. Triple-buffered LDS (144 KB).
// ROUND-4 VERSION (session best: 40.6 us, 955 TF) -- restored after rounds 5/6
// regressions. Fine per-phase interleave (T3): each K-step = 2 phases of
// {8 ds_read_b128 ; 3 stage-issues for t+2 ; lgkmcnt(0)+sched_barrier ; setprio(1)
// 16-MFMA cluster setprio(0) ; barrier}. Counted vmcnt(6) once per K-step (T4,
// never 0 mid-loop). Hazards: exit barrier of step t separates all readers of
// buf[t%3] from its overwrite at step t+1 (stage targets (t+3)%3 = t%3), and
// vmcnt(6) with 12 outstanding guarantees tile t+1's 6 per-wave loads landed.
// Tried and rejected: +2 barriers/phase (r5: 44.4us), A-operand global->VGPR
// bypass (r6: 99us -- lane-strided A-frag loads are uncoalesced 16B gathers;
// LDS staging via gll16 IS the coalescing engine). Structure floor est. ~23 us
// (LDS-read-bound: 128KB/K-step ~ 1540cyc > MFMA 1242cyc).
__global__ __launch_bounds__(512, 2)
void gemm_value_p(const bf16* __restrict__ Wr, const bf16* __restrict__ fTpad,
                  bf16* __restrict__ value, const float* __restrict__ b0,
                  const float* __restrict__ b1) {
  __shared__ bf16 smem3[3 * 24576];      // 3 x (A 256x64 + B 128x64) = 147456 B
  const int z = blockIdx.y;              // pair-major: t = z&1, b = z>>1
  const int tt = z & 1, bb = z >> 1, zold = tt * 16 + bb;
  const bf16* Ab = Wr + (size_t)tt * 589824;
  const bf16* Bb = fTpad + (size_t)zold * ZSTR;
  const int n0 = blockIdx.x * 128;
  const int tid = threadIdx.x;
  const int lane = tid & 63, wave = tid >> 6;
  const int wm = (wave >> 1) * 64, wn = (wave & 1) * 64;   // 4M x 2N wave grid, 64x64/wave
  const int fr = lane & 15, fq = lane >> 4;

  // staging addresses: XOR chunk swizzle p = c ^ (row & 7), linear LDS dest (m173)
  const bf16* srcA[4]; int ldsA[4];
  #pragma unroll
  for (int s = 0; s < 4; ++s) {
    int q = s * 512 + tid;               // 2048 16B chunks cover A 256x64
    int row = q >> 3, c = (q & 7) ^ (row & 7);
    ldsA[s] = __builtin_amdgcn_readfirstlane(s * 4096 + wave * 512);
    srcA[s] = Ab + (size_t)row * 2304 + c * 8;
  }
  const bf16* srcB[2]; int ldsB[2];
  #pragma unroll
  for (int s = 0; s < 2; ++s) {
    int q = s * 512 + tid;               // 1024 chunks cover B 128x64
    int row = q >> 3, c = (q & 7) ^ (row & 7);
    ldsB[s] = __builtin_amdgcn_readfirstlane(s * 4096 + wave * 512);
    int jb = n0 + row;
    srcB[s] = Bb + (size_t)(((jb >> 5) + 1) * 34 + (jb & 31) + 1) * C_ + c * 8;
  }

  int lA[2][4], lB[2][4];
  #pragma unroll
  for (int h = 0; h < 2; ++h) {
    #pragma unroll
    for (int i = 0; i < 4; ++i) {
      int rr = wm + i * 16 + fr;
      lA[h][i] = rr * 64 + (((h * 4) + fq) ^ (rr & 7)) * 8;
      int rc = wn + i * 16 + fr;
      lB[h][i] = rc * 64 + (((h * 4) + fq) ^ (rc & 7)) * 8;
    }
  }

  auto STAGE = [&](int t, int bufi) {    // full-tile stage (prologue only)
    int k0 = t * 64;
    int d = k0 >> 8;
    int kh = d / 3, kw = d - kh * 3;
    int boff = ((kh - 1) * 34 + (kw - 1)) * C_ + (k0 & 255);
    bf16* As = smem3 + bufi * 24576;
    bf16* Bs = As + 16384;
    #pragma unroll
    for (int s = 0; s < 4; ++s) gll16(srcA[s] + k0, As + ldsA[s]);
    #pragma unroll
    for (int s = 0; s < 2; ++s) gll16(srcB[s] + boff, Bs + ldsB[s]);
  };

  f32x4 acc[4][4];
  #pragma unroll
  for (int i = 0; i < 4; ++i)
    #pragma unroll
    for (int j = 0; j < 4; ++j) acc[i][j] = 0.f;

  STAGE(0, 0);
  STAGE(1, 1);                           // 12 outstanding
  asm volatile("s_waitcnt vmcnt(6)" ::: "memory");   // tile0 landed
  __builtin_amdgcn_s_barrier();

  int cur = 0;
  #pragma unroll 1
  for (int t = 0; t < 36; ++t) {
    bf16* As = smem3 + cur * 24576;
    bf16* Bs = As + 16384;
    int nx = cur + 2; if (nx >= 3) nx -= 3;
    bf16* An = smem3 + nx * 24576;
    bf16* Bn = An + 16384;
    const bool pf = (t + 2 < 36);
    int k2 = (t + 2) * 64;
    int d2 = k2 >> 8;
    int kh2 = d2 / 3, kw2 = d2 - kh2 * 3;
    int boff2 = ((kh2 - 1) * 34 + (kw2 - 1)) * C_ + (k2 & 255);

    // ---------------- phase A: h=0 ----------------
    {
      bf16x8 af[4], bv[4];
      #pragma unroll
      for (int i = 0; i < 4; ++i) af[i] = *(const bf16x8*)(As + lA[0][i]);
      #pragma unroll
      for (int j = 0; j < 4; ++j) bv[j] = *(const bf16x8*)(Bs + lB[0][j]);
      if (pf) {
        gll16(srcA[0] + k2, An + ldsA[0]);
        gll16(srcA[1] + k2, An + ldsA[1]);
        gll16(srcB[0] + boff2, Bn + ldsB[0]);
      }
      asm volatile("s_waitcnt lgkmcnt(0)" ::: "memory");
      __builtin_amdgcn_sched_barrier(0);
      __builtin_amdgcn_s_setprio(1);
      #pragma unroll
      for (int i = 0; i < 4; ++i)
        #pragma unroll
        for (int j = 0; j < 4; ++j)
          acc[i][j] = __builtin_amdgcn_mfma_f32_16x16x32_bf16(af[i], bv[j], acc[i][j], 0, 0, 0);
      __builtin_amdgcn_s_setprio(0);
    }
    __builtin_amdgcn_s_barrier();

    // ---------------- phase B: h=1 ----------------
    {
      bf16x8 af[4], bv[4];
      #pragma unroll
      for (int i = 0; i < 4; ++i) af[i] = *(const bf16x8*)(As + lA[1][i]);
      #pragma unroll
      for (int j = 0; j < 4; ++j) bv[j] = *(const bf16x8*)(Bs + lB[1][j]);
      if (pf) {
        gll16(srcA[2] + k2, An + ldsA[2]);
        gll16(srcA[3] + k2, An + ldsA[3]);
        gll16(srcB[1] + boff2, Bn + ldsB[1]);
      }
      asm volatile("s_waitcnt lgkmcnt(0)" ::: "memory");
      __builtin_amdgcn_sched_barrier(0);
      __builtin_amdgcn_s_setprio(1);
      #pragma unroll
      for (int i = 0; i < 4; ++i)
        #pragma unroll
        for (int j = 0; j < 4; ++j)
          acc[i][j] = __builtin_amdgcn_mfma_f32_16x16x32_bf16(af[i], bv[j], acc[i][j], 0, 0, 0);
      __builtin_amdgcn_s_setprio(0);
    }
    // tile t+1's loads must be landed before next step reads buf[(t+1)%3]:
    // outstanding = (t+1)'s 6 + (t+2)'s 6 (if staged) -> counted wait, never 0 mid-loop
    if (t < 34)       asm volatile("s_waitcnt vmcnt(6)" ::: "memory");
    else if (t == 34) asm volatile("s_waitcnt vmcnt(0)" ::: "memory");
    __builtin_amdgcn_s_barrier();

    ++cur; if (cur >= 3) cur = 0;
  }

  // epilogue: row = wm + i*16 + fq*4 + r (= out channel c), col = n0 + wn + j*16 + fr
  const float* bias = tt ? b1 : b0;
  #pragma unroll
  for (int i = 0; i < 4; ++i) {
    #pragma unroll
    for (int j = 0; j < 4; ++j) {
      int col = n0 + wn + j * 16 + fr;
      #pragma unroll
      for (int r = 0; r < 4; ++r) {
        int row = wm + i * 16 + fq * 4 + r;
        value[(size_t)z * ((size_t)C_ * HW_) + (size_t)row * 1024 + col] =
            (bf16)(acc[i][j][r] + bias[row]);
      }
    }
  }
}

extern "C" void kernel_launch(void* const* d_in, const int* in_sizes, int n_in,
                              void* d_out, int out_size, void* d_ws, size_t ws_size,
                              hipStream_t stream) {
  const float* f0 = (const float*)d_in[0];
  const float* f1 = (const float*)d_in[1];
  const float* w0 = (const float*)d_in[2];
  const float* b0 = (const float*)d_in[3];
  const float* w1 = (const float*)d_in[4];
  const float* b1 = (const float*)d_in[5];
  const float* fusion_w = (const float*)d_in[6];
  const float* fusion_b = (const float*)d_in[7];
  float* out = (float*)d_out;

  // workspace (~105 MB peak):
  //   aff [2 tasks] at 0..67.1M; Mbuf written IN PLACE over aff0 by fusion_conv2;
  //   fTpad / Wr / value / rn above (value kept separate from aff).
  char* ws = (char*)d_ws;
  bf16* aff   = (bf16*)ws;                       // 67,108,864  [2 tasks]
  bf16* Mbuf  = (bf16*)ws;                       // in-place over aff0
  bf16* fTpad = (bf16*)(ws + 67108864ull);       // 18,939,904
  bf16* Wr    = (bf16*)(ws + 86048768ull);       //  2,359,296
  bf16* value = (bf16*)(ws + 88408064ull);       // 16,777,216
  float* rn   = (float*)(ws + 105185280ull);     //    131,072

  prep_fat<<<5632, 256, 0, stream>>>(f0, f1, w0, w1, fTpad, rn, Wr);
  // aff[z][i][j] = (sum_c fT[z][i][c] * fT[z][j][c]) * rn[z][i] * rn[z][j]  (SYRK, 36 tiles/z)
  gemm_aff<<<dim3(36, 1, 32), 256, 0, stream>>>(fTpad, rn, aff);
  // value[zp][c][j] = conv(f_t, w_t)[b][c][j] + bias_t[c]   (pipelined 8-wave, 1 block/CU)
  gemm_value_p<<<dim3(8, 32), 512, 0, stream>>>(Wr, fTpad, value, b0, b1);
  fusion_conv2<<<16384, 256, 0, stream>>>(aff, fusion_w, fusion_b, Mbuf);
  // out[t][b][c][j] = 0.5 * sum_k value[zp][c][k] * Mbuf[b][j][k] + 0.5 * f_t[b][c][j]
  gemm_attend<<<dim3(8, 2, 32), 256, 0, stream>>>(value, Mbuf, f0, f1, out);
}